// Round 19
// baseline (135.549 us; speedup 1.0000x reference)
//
#include <hip/hip_runtime.h>

#define INC 5
#define H1C 16
#define H2C 32
#define KCL 256

// fallback (rescan) params
#define NBINS 40
#define BINSZ 2500
#define MAXCHUNK 12

// partition params
#define PB_SHIFT 9
#define PB_SZ 512               // nodes per bin
#define PB_NBMAX 256
#define PB_C 18432              // bucket capacity per bin (mean 16384 + 16 sigma)
#define PB_M 6144               // edges per partition block
#define PB_ETPB 6               // PB_M / 1024
#define PB_S 3                  // phase-2 sub-splits per bin (gather: 588 blocks)
#define PB_GMAX 6144            // max entries per gather block = ceil(PB_C/PB_S)
#define PB_GETG 6               // ceil(PB_GMAX/1024)

#define POOL_NB 1536            // pool blocks (6/CU at 32KB LDS): max TLP
#define PCH 256                 // max nodes per pool block chunk

typedef __attribute__((address_space(1))) const unsigned gls_src;
typedef __attribute__((address_space(3))) unsigned gls_dst;

// ---------------------------------------------------------------------------
// Fused setup: x8 expansion + gcur init + int64/int32 detect.
__global__ void k_setup(const float* __restrict__ x, float* __restrict__ x8,
                        const unsigned int* __restrict__ ei, int* __restrict__ flag,
                        unsigned* __restrict__ gcur, int N, int NB) {
    int n = blockIdx.x * blockDim.x + threadIdx.x;
    if (n < N) {
        const float* xr = x + (size_t)n * INC;
        float4* o = (float4*)(x8 + (size_t)n * 8);
        o[0] = make_float4(xr[0], xr[1], xr[2], xr[3]);
        o[1] = make_float4(xr[4], 0.0f, 0.0f, 0.0f);
    }
    if (blockIdx.x == 0) {
        if (threadIdx.x < (unsigned)NB) gcur[threadIdx.x] = (unsigned)threadIdx.x * PB_C;
        if (threadIdx.x == 0) {
            int is64 = 1;
            for (int i = 1; i < 32; i += 2)
                if (ei[i] != 0u) is64 = 0;
            *flag = is64;
        }
    }
}

// standalone detect for the fallback path
__global__ void k_detect(const unsigned int* __restrict__ ei, int* __restrict__ flag) {
    if (blockIdx.x == 0 && threadIdx.x == 0) {
        int is64 = 1;
        for (int i = 1; i < 32; i += 2)
            if (ei[i] != 0u) is64 = 0;
        *flag = is64;
    }
}

// ---------------------------------------------------------------------------
// Phase 1: partition edges into dst-bins (LDS histogram + counting sort +
// coalesced bucket writes of packed entries src<<9 | dst&511).
__global__ __launch_bounds__(1024) void k_part(const unsigned int* __restrict__ ei,
                                               const int* __restrict__ flag,
                                               unsigned* __restrict__ gcur,
                                               unsigned* __restrict__ bucket,
                                               int E, int NB) {
    __shared__ int hist[PB_NBMAX];
    __shared__ int lbase[PB_NBMAX];
    __shared__ unsigned gbase[PB_NBMAX];
    __shared__ unsigned sorted[PB_M];
    __shared__ unsigned char sbin[PB_M];

    const int tid = threadIdx.x;
    const int e0 = blockIdx.x * PB_M;
    int m = E - e0; if (m > PB_M) m = PB_M;

    for (int i = tid; i < PB_NBMAX; i += 1024) hist[i] = 0;
    __syncthreads();

    const int is64 = *flag;  // uniform
    unsigned ee[PB_ETPB]; int eb[PB_ETPB]; int er[PB_ETPB];

#pragma unroll
    for (int ii = 0; ii < PB_ETPB; ii++) {
        const int off = tid + ii * 1024;
        eb[ii] = -1; ee[ii] = 0u; er[ii] = 0;
        if (off < m) {
            const int e = e0 + off;
            unsigned d, s;
            if (is64) { d = ei[2 * ((size_t)E + (size_t)e)]; s = ei[2 * (size_t)e]; }
            else      { d = ei[(size_t)E + (size_t)e];       s = ei[(size_t)e]; }
            const int b = (int)(d >> PB_SHIFT);
            eb[ii] = b;
            ee[ii] = (s << PB_SHIFT) | (d & (PB_SZ - 1));
            er[ii] = atomicAdd(&hist[b], 1);
        }
    }
    __syncthreads();

    // single-wave exclusive scan of 256-entry hist
    if (tid < 64) {
        const int base = tid * 4;
        int vals[4]; int s = 0;
#pragma unroll
        for (int k = 0; k < 4; k++) { vals[k] = hist[base + k]; s += vals[k]; }
        int t = s;
#pragma unroll
        for (int off = 1; off < 64; off <<= 1) {
            int y = __shfl_up(t, off);
            if (tid >= off) t += y;
        }
        int ex = t - s;
#pragma unroll
        for (int k = 0; k < 4; k++) { lbase[base + k] = ex; ex += vals[k]; }
    }
    if (tid >= 64 && tid < 64 + NB) {
        const int b = tid - 64;
        gbase[b] = atomicAdd(&gcur[b], (unsigned)hist[b]);
    }
    __syncthreads();

#pragma unroll
    for (int ii = 0; ii < PB_ETPB; ii++) {
        if (eb[ii] >= 0) {
            const int j = lbase[eb[ii]] + er[ii];
            sorted[j] = ee[ii];
            sbin[j] = (unsigned char)eb[ii];
        }
    }
    __syncthreads();

    for (int j = tid; j < m; j += 1024) {
        const int b = (int)sbin[j];
        const unsigned g = gbase[b] + (unsigned)(j - lbase[b]);
        if (g < (unsigned)(b + 1) * PB_C) bucket[g] = sorted[j];  // overflow guard
    }
}

// ---------------------------------------------------------------------------
// Phase 2 (atomic-free accumulate): counting-sort + register accumulation.
__global__ __launch_bounds__(1024) void k_gather(const unsigned* __restrict__ bucket,
                                                 const unsigned* __restrict__ gcur,
                                                 const float* __restrict__ x8,
                                                 float* __restrict__ part,
                                                 int N, int NB) {
    __shared__ unsigned sorted[PB_GMAX];   // 24 KB
    __shared__ int hist[PB_SZ];
    __shared__ int lbase[PB_SZ];
    __shared__ float stage[PB_SZ * 6];     // 12 KB

    const int b = blockIdx.x / PB_S;
    const int sub = blockIdx.x % PB_S;
    const int tid = threadIdx.x;
    const int lo = b << PB_SHIFT;
    int hi = lo + PB_SZ; if (hi > N) hi = N;
    const int nloc = hi - lo;

    int cnt = (int)(gcur[b] - (unsigned)b * PB_C);
    if (cnt > PB_C) cnt = PB_C;
    const int i0 = (cnt * sub) / PB_S;
    const int i1 = (cnt * (sub + 1)) / PB_S;
    const int m = i1 - i0;
    const unsigned* bk = bucket + (size_t)b * PB_C + i0;

    for (int i = tid; i < PB_SZ; i += 1024) hist[i] = 0;
    __syncthreads();

    unsigned ee[PB_GETG]; int edl[PB_GETG]; int er[PB_GETG];
#pragma unroll
    for (int ii = 0; ii < PB_GETG; ii++) {
        const int off = tid + ii * 1024;
        edl[ii] = -1; ee[ii] = 0u; er[ii] = 0;
        if (off < m) {
            const unsigned e = bk[off];
            const int dl = (int)(e & (PB_SZ - 1));
            edl[ii] = dl;
            ee[ii] = e;
            er[ii] = atomicAdd(&hist[dl], 1);
        }
    }
    __syncthreads();

    // single-wave exclusive scan of 512-entry hist
    if (tid < 64) {
        const int base = tid * 8;
        int vals[8]; int s = 0;
#pragma unroll
        for (int k = 0; k < 8; k++) { vals[k] = hist[base + k]; s += vals[k]; }
        int t = s;
#pragma unroll
        for (int off = 1; off < 64; off <<= 1) {
            int y = __shfl_up(t, off);
            if (tid >= off) t += y;
        }
        int ex = t - s;
#pragma unroll
        for (int k = 0; k < 8; k++) { lbase[base + k] = ex; ex += vals[k]; }
    }
    __syncthreads();

#pragma unroll
    for (int ii = 0; ii < PB_GETG; ii++)
        if (edl[ii] >= 0) sorted[lbase[edl[ii]] + er[ii]] = ee[ii];
    __syncthreads();

    const int node = tid & (PB_SZ - 1);
    const int half = tid >> PB_SHIFT;      // 0 or 1
    const int start = lbase[node];
    const int len = hist[node];
    const int js = start + (half ? (len >> 1) : 0);
    const int je = start + (half ? len : (len >> 1));
    float a0 = 0.f, a1 = 0.f, a2 = 0.f, a3 = 0.f, a4 = 0.f;
    for (int j = js; j < je; j++) {
        const unsigned s = sorted[j] >> PB_SHIFT;
        const float4 xr4 = *(const float4*)(x8 + (size_t)s * 8);
        const float xr5 = x8[(size_t)s * 8 + 4];
        a0 += xr4.x; a1 += xr4.y; a2 += xr4.z; a3 += xr4.w; a4 += xr5;
    }
    if (half) {
        float* st = stage + node * 6;
        st[0] = a0; st[1] = a1; st[2] = a2; st[3] = a3; st[4] = a4;
    }
    __syncthreads();
    if (!half && node < nloc) {
        const float* st = stage + node * 6;
        float* o = part + (size_t)sub * ((size_t)N * 6) + (size_t)(lo + node) * 6;
        o[0] = a0 + st[0];
        o[1] = a1 + st[1];
        o[2] = a2 + st[2];
        o[3] = a3 + st[3];
        o[4] = a4 + st[4];
        o[5] = (float)len;
    }
}

// ---------------------------------------------------------------------------
// Fallback binned-rescan edge kernel.
__global__ __launch_bounds__(1024) void k_edge_bin(const unsigned int* __restrict__ ei,
                                                   const float* __restrict__ x,
                                                   const int* __restrict__ flag,
                                                   float* __restrict__ part,
                                                   int E, int nchunk, int N) {
    __shared__ float acc[BINSZ * 6];
    const int bin = blockIdx.x % NBINS;
    const int chunk = blockIdx.x / NBINS;
    const int lo = bin * BINSZ;
    const int hi = (lo + BINSZ < N) ? (lo + BINSZ) : N;
    const int nloc = hi - lo;
    for (int i = threadIdx.x; i < nloc * 6; i += 1024) acc[i] = 0.0f;
    __syncthreads();

    const int is64 = *flag;
    const long long ce = ((long long)E + nchunk - 1) / nchunk;
    const long long e0 = (long long)chunk * ce;
    long long e1 = e0 + ce;
    if (e1 > E) e1 = E;

    for (long long e = e0 + threadIdx.x; e < e1; e += 1024) {
        const int d = is64 ? (int)ei[2 * ((size_t)E + (size_t)e)] : (int)ei[(size_t)E + (size_t)e];
        if (d >= lo && d < hi) {
            const int s = is64 ? (int)ei[2 * (size_t)e] : (int)ei[(size_t)e];
            const float* xr = x + (size_t)s * INC;
            float* a = acc + (d - lo) * 6;
            atomicAdd(a + 0, xr[0]);
            atomicAdd(a + 1, xr[1]);
            atomicAdd(a + 2, xr[2]);
            atomicAdd(a + 3, xr[3]);
            atomicAdd(a + 4, xr[4]);
            atomicAdd(a + 5, 1.0f);
        }
    }
    __syncthreads();
    float* o = part + (size_t)chunk * ((size_t)N * 6) + (size_t)lo * 6;
    for (int i = threadIdx.x; i < nloc * 6; i += 1024) o[i] = acc[i];
}

// ---------------------------------------------------------------------------
// Reduce partials + node update (FALLBACK PATH ONLY).
__global__ void k_node2(const float* __restrict__ x, const float* __restrict__ part,
                        const float* __restrict__ W1, const float* __restrict__ root1,
                        const float* __restrict__ b1, float* __restrict__ h,
                        int N, int nchunk) {
    int n = blockIdx.x * blockDim.x + threadIdx.x;
    if (n >= N) return;
    float s[6] = {0.f, 0.f, 0.f, 0.f, 0.f, 0.f};
    for (int c = 0; c < nchunk; c++) {
        const float* p = part + (size_t)c * ((size_t)N * 6) + (size_t)n * 6;
#pragma unroll
        for (int j = 0; j < 6; j++) s[j] += p[j];
    }
    const float inv = 1.0f / fmaxf(s[5], 1.0f);
    float xs[INC], xv[INC];
#pragma unroll
    for (int c = 0; c < INC; c++) {
        xs[c] = s[c] * inv;
        xv[c] = x[(size_t)n * INC + c];
    }
    float hv[H1C];
#pragma unroll
    for (int j = 0; j < H1C; j++) {
        float v = b1[j];
#pragma unroll
        for (int c = 0; c < INC; c++)
            v = fmaf(xs[c], W1[c * H1C + j], fmaf(xv[c], root1[c * H1C + j], v));
        hv[j] = fmaxf(v, 0.0f);
    }
    float4* hp = (float4*)(h + (size_t)n * H1C);
#pragma unroll
    for (int q = 0; q < 4; q++)
        hp[q] = make_float4(hv[4 * q], hv[4 * q + 1], hv[4 * q + 2], hv[4 * q + 3]);
}

// ---------------------------------------------------------------------------
// Pooling GEMM, depth-4 register pipeline (R11-exact), PB_S-generic h-compute.
__global__ __launch_bounds__(256) void k_pool(const float* __restrict__ pos,
                                              const float* __restrict__ h,
                                              const float* __restrict__ part,
                                              const float* __restrict__ x8,
                                              const float* __restrict__ W1,
                                              const float* __restrict__ root1,
                                              const float* __restrict__ b1,
                                              float* __restrict__ xp_part, int N, int nb) {
    __shared__ float hbuf[PCH * H1C];
    __shared__ float sred[2][32][64];
    const int tid = threadIdx.x;
    const int lane = tid & 63;
    const int w = tid >> 6;
    const int chunk = (N + nb - 1) / nb;
    const int n0 = blockIdx.x * chunk;
    const int n1 = min(n0 + chunk, N);
    const int cnt = (n1 > n0) ? (n1 - n0) : 0;

    if (part) {
        if (tid < cnt) {
            const int n = n0 + tid;
            float s[6] = {0.f, 0.f, 0.f, 0.f, 0.f, 0.f};
#pragma unroll
            for (int c = 0; c < PB_S; c++) {
                const float* p = part + (size_t)c * ((size_t)N * 6) + (size_t)n * 6;
#pragma unroll
                for (int j = 0; j < 6; j++) s[j] += p[j];
            }
            const float inv = 1.0f / fmaxf(s[5], 1.0f);
            float xs[INC], xv[INC];
#pragma unroll
            for (int c = 0; c < INC; c++) {
                xs[c] = s[c] * inv;
                xv[c] = x8[(size_t)n * 8 + c];
            }
#pragma unroll
            for (int j = 0; j < H1C; j++) {
                float v = b1[j];
#pragma unroll
                for (int c = 0; c < INC; c++)
                    v = fmaf(xs[c], W1[c * H1C + j], fmaf(xv[c], root1[c * H1C + j], v));
                hbuf[tid * H1C + j] = fmaxf(v, 0.0f);
            }
        }
    } else {
        const size_t maxh = (size_t)N * H1C - 4;
        for (int ii = w; ii * 256 < cnt * H1C; ii += 4) {
            size_t fi = (size_t)n0 * H1C + (size_t)ii * 256 + (size_t)lane * 4;
            if (fi > maxh) fi = maxh;
            __builtin_amdgcn_global_load_lds((gls_src*)(h + fi),
                                             (gls_dst*)&hbuf[ii * 256], 16, 0, 0);
        }
    }
    __syncthreads();

    float acc[4][H1C];
#pragma unroll
    for (int c = 0; c < 4; c++)
#pragma unroll
        for (int d = 0; d < H1C; d++) acc[c][d] = 0.0f;

    const float4* pos4 = (const float4*)pos;
    const float4 z4 = make_float4(0.f, 0.f, 0.f, 0.f);

#define LDP(dst, i)                                                        \
    {                                                                      \
        const int _i = (i);                                                \
        if (_i < cnt) dst = pos4[((size_t)n0 + _i) * 64 + lane];           \
    }
#define CMP(i, p)                                                          \
    {                                                                      \
        const int _i = (i);                                                \
        if (_i < cnt) {                                                    \
            const float4 h0 = *(const float4*)&hbuf[_i * H1C + 0];         \
            const float4 h1 = *(const float4*)&hbuf[_i * H1C + 4];         \
            const float4 h2 = *(const float4*)&hbuf[_i * H1C + 8];         \
            const float4 h3 = *(const float4*)&hbuf[_i * H1C + 12];        \
            const float pk[4] = {p.x, p.y, p.z, p.w};                      \
            const float hv[H1C] = {h0.x, h0.y, h0.z, h0.w,                 \
                                   h1.x, h1.y, h1.z, h1.w,                 \
                                   h2.x, h2.y, h2.z, h2.w,                 \
                                   h3.x, h3.y, h3.z, h3.w};                \
            _Pragma("unroll")                                              \
            for (int c = 0; c < 4; c++)                                    \
                _Pragma("unroll")                                          \
                for (int d = 0; d < H1C; d++)                              \
                    acc[c][d] = fmaf(pk[c], hv[d], acc[c][d]);             \
        }                                                                  \
    }

    float4 A0 = z4, A1 = z4, A2 = z4, A3 = z4;
    float4 B0 = z4, B1 = z4, B2 = z4, B3 = z4;
    float4 C0 = z4, C1 = z4, C2 = z4, C3 = z4;
    float4 D0 = z4, D1 = z4, D2 = z4, D3 = z4;
    LDP(A0, w + 0)  LDP(A1, w + 4)  LDP(A2, w + 8)  LDP(A3, w + 12)
    LDP(B0, w + 16) LDP(B1, w + 20) LDP(B2, w + 24) LDP(B3, w + 28)
    LDP(C0, w + 32) LDP(C1, w + 36) LDP(C2, w + 40) LDP(C3, w + 44)
    LDP(D0, w + 48) LDP(D1, w + 52) LDP(D2, w + 56) LDP(D3, w + 60)
    for (int i = w; i < cnt; i += 64) {
        CMP(i + 0, A0)  CMP(i + 4, A1)  CMP(i + 8, A2)  CMP(i + 12, A3)
        LDP(A0, i + 64) LDP(A1, i + 68) LDP(A2, i + 72) LDP(A3, i + 76)
        CMP(i + 16, B0) CMP(i + 20, B1) CMP(i + 24, B2) CMP(i + 28, B3)
        LDP(B0, i + 80) LDP(B1, i + 84) LDP(B2, i + 88) LDP(B3, i + 92)
        CMP(i + 32, C0) CMP(i + 36, C1) CMP(i + 40, C2) CMP(i + 44, C3)
        LDP(C0, i + 96) LDP(C1, i + 100) LDP(C2, i + 104) LDP(C3, i + 108)
        CMP(i + 48, D0) CMP(i + 52, D1) CMP(i + 56, D2) CMP(i + 60, D3)
        LDP(D0, i + 112) LDP(D1, i + 116) LDP(D2, i + 120) LDP(D3, i + 124)
    }
#undef LDP
#undef CMP

    __syncthreads();
#pragma unroll
    for (int ch = 0; ch < 2; ch++) {
        if (w == 1 || w == 3) {
            float* sl = &sred[(w - 1) >> 1][0][0] + lane;
#pragma unroll
            for (int v = 0; v < 32; v++) sl[v * 64] = acc[ch * 2 + (v >> 4)][v & 15];
        }
        __syncthreads();
        if (w == 0 || w == 2) {
            const float* sl = &sred[w >> 1][0][0] + lane;
#pragma unroll
            for (int v = 0; v < 32; v++) acc[ch * 2 + (v >> 4)][v & 15] += sl[v * 64];
        }
        __syncthreads();
        if (w == 2) {
            float* sl = &sred[0][0][0] + lane;
#pragma unroll
            for (int v = 0; v < 32; v++) sl[v * 64] = acc[ch * 2 + (v >> 4)][v & 15];
        }
        __syncthreads();
        if (w == 0) {
            const float* sl = &sred[0][0][0] + lane;
#pragma unroll
            for (int v = 0; v < 32; v++) acc[ch * 2 + (v >> 4)][v & 15] += sl[v * 64];
        }
        __syncthreads();
    }
    if (w == 0) {
        float* o = xp_part + (size_t)blockIdx.x * (KCL * H1C);
#pragma unroll
        for (int c = 0; c < 4; c++) {
            float* oc = o + (4 * lane + c) * H1C;
            *(float4*)(oc + 0)  = make_float4(acc[c][0],  acc[c][1],  acc[c][2],  acc[c][3]);
            *(float4*)(oc + 4)  = make_float4(acc[c][4],  acc[c][5],  acc[c][6],  acc[c][7]);
            *(float4*)(oc + 8)  = make_float4(acc[c][8],  acc[c][9],  acc[c][10], acc[c][11]);
            *(float4*)(oc + 12) = make_float4(acc[c][12], acc[c][13], acc[c][14], acc[c][15]);
        }
    }
}

// ---------------------------------------------------------------------------
__global__ __launch_bounds__(1024) void k_xpred(const float* __restrict__ xp_part,
                                                float* __restrict__ xp, int nb) {
    __shared__ float r[1024];
    const int li = threadIdx.x & 63;
    const int sub = threadIdx.x >> 6;      // 0..15
    const int i = blockIdx.x * 64 + li;
    float s = 0.0f;
    for (int b = sub; b < nb; b += 16) s += xp_part[(size_t)b * (KCL * H1C) + i];
    r[threadIdx.x] = s;
    __syncthreads();
    if (threadIdx.x < 512) r[threadIdx.x] += r[threadIdx.x + 512];
    __syncthreads();
    if (threadIdx.x < 256) r[threadIdx.x] += r[threadIdx.x + 256];
    __syncthreads();
    if (threadIdx.x < 128) r[threadIdx.x] += r[threadIdx.x + 128];
    __syncthreads();
    if (threadIdx.x < 64) xp[i] = r[threadIdx.x] + r[threadIdx.x + 64];
}

// ---------------------------------------------------------------------------
// Tail: adj strictly positive => mask all-ones, deg2 = 256.
__global__ __launch_bounds__(256) void k_tail(const float* __restrict__ xp,
                                              const float* __restrict__ W2,
                                              const float* __restrict__ root2,
                                              const float* __restrict__ b2,
                                              const float* __restrict__ lw1,
                                              const float* __restrict__ lb1,
                                              const float* __restrict__ lw2,
                                              const float* __restrict__ lb2,
                                              float* __restrict__ out) {
    __shared__ float red[4][H2C];
    __shared__ float bcast[H2C];
    const int t = threadIdx.x;
    const int wv = t >> 6;
    const int lane = t & 63;

    float row[H1C];
#pragma unroll
    for (int c = 0; c < H1C; c++) row[c] = xp[t * H1C + c];

    float v1[H2C];
#pragma unroll
    for (int j = 0; j < H2C; j++) {
        float v = 0.0f;
#pragma unroll
        for (int c = 0; c < H1C; c++) v = fmaf(row[c], W2[c * H2C + j], v);
        v1[j] = v;
    }
#pragma unroll
    for (int off = 1; off < 64; off <<= 1) {
#pragma unroll
        for (int j = 0; j < H2C; j++) v1[j] += __shfl_xor(v1[j], off);
    }
    if (lane == 0) {
#pragma unroll
        for (int j = 0; j < H2C; j++) red[wv][j] = v1[j];
    }
    __syncthreads();
    if (t < H2C) bcast[t] = red[0][t] + red[1][t] + red[2][t] + red[3][t];
    __syncthreads();

    float v2[H2C];
#pragma unroll
    for (int j = 0; j < H2C; j++) {
        float v = bcast[j] * (1.0f / KCL) + b2[j];
#pragma unroll
        for (int c = 0; c < H1C; c++) v = fmaf(row[c], root2[c * H2C + j], v);
        v2[j] = fmaxf(v, 0.0f);
    }
#pragma unroll
    for (int off = 1; off < 64; off <<= 1) {
#pragma unroll
        for (int j = 0; j < H2C; j++) v2[j] += __shfl_xor(v2[j], off);
    }
    if (lane == 0) {
#pragma unroll
        for (int j = 0; j < H2C; j++) red[wv][j] = v2[j];
    }
    __syncthreads();

    if (t == 0) {
        float g[H2C];
#pragma unroll
        for (int j = 0; j < H2C; j++)
            g[j] = (red[0][j] + red[1][j] + red[2][j] + red[3][j]) * (1.0f / KCL);
        float u[8];
#pragma unroll
        for (int a = 0; a < 8; a++) {
            float v = lb1[a];
#pragma unroll
            for (int j = 0; j < H2C; j++) v = fmaf(g[j], lw1[j * 8 + a], v);
            u[a] = v > 0.0f ? v : 0.1f * v;
        }
#pragma unroll
        for (int o = 0; o < 2; o++) {
            float v = lb2[o];
#pragma unroll
            for (int a = 0; a < 8; a++) v = fmaf(u[a], lw2[a * 2 + o], v);
            out[o] = v;
        }
    }
}

// ---------------------------------------------------------------------------
extern "C" void kernel_launch(void* const* d_in, const int* in_sizes, int n_in,
                              void* d_out, int out_size, void* d_ws, size_t ws_size,
                              hipStream_t stream) {
    const float* x         = (const float*)d_in[0];
    const unsigned int* ei = (const unsigned int*)d_in[1];
    // d_in[2] = edge_attr: unused (adj has no exact zeros -> mask all-ones)
    const float* pos   = (const float*)d_in[3];
    const float* W1    = (const float*)d_in[4];
    const float* root1 = (const float*)d_in[5];
    const float* b1    = (const float*)d_in[6];
    const float* W2    = (const float*)d_in[7];
    const float* root2 = (const float*)d_in[8];
    const float* b2    = (const float*)d_in[9];
    const float* lw1   = (const float*)d_in[10];
    const float* lb1   = (const float*)d_in[11];
    const float* lw2   = (const float*)d_in[12];
    const float* lb2   = (const float*)d_in[13];
    float* out = (float*)d_out;

    const int N = in_sizes[0] / INC;  // 100000
    const int E = in_sizes[1] / 2;    // 3200000
    const int NB = (N + PB_SZ - 1) >> PB_SHIFT;

    // workspace prefix (floats): [xp 4096][flag 16][h N*16][REGION ...]
    float* ws    = (float*)d_ws;
    float* xp    = ws;
    int*   flag  = (int*)(xp + KCL * H1C);
    float* h     = (float*)(flag + 16);
    float* regio = h + (size_t)N * H1C;

    const size_t pref_floats = (size_t)(KCL * H1C) + 16 + (size_t)N * H1C;
    const size_t region_floats = ws_size / 4 > pref_floats ? ws_size / 4 - pref_floats : 0;
    const size_t slab_floats = (size_t)POOL_NB * (KCL * H1C);
    const size_t buck_floats = (size_t)NB * PB_C + 256;
    const size_t fast_floats = (size_t)PB_S * N * 6 + (size_t)N * 8 +
                               (buck_floats > slab_floats ? buck_floats : slab_floats);

    if (region_floats >= fast_floats && N <= 131072 && NB <= PB_NBMAX) {
        float* part      = regio;
        float* x8        = part + (size_t)PB_S * N * 6;
        unsigned* bucket = (unsigned*)(x8 + (size_t)N * 8);
        unsigned* gcur   = bucket + (size_t)NB * PB_C;
        const int P = (E + PB_M - 1) / PB_M;

        k_setup<<<(N + 255) / 256, 256, 0, stream>>>(x, x8, ei, flag, gcur, N, NB);
        k_part<<<P, 1024, 0, stream>>>(ei, flag, gcur, bucket, E, NB);
        k_gather<<<NB * PB_S, 1024, 0, stream>>>(bucket, gcur, x8, part, N, NB);

        float* xp_part = (float*)bucket;   // overwrites bucket (dead after gather)
        k_pool<<<POOL_NB, 256, 0, stream>>>(pos, nullptr, part, x8, W1, root1, b1,
                                            xp_part, N, POOL_NB);
        k_xpred<<<64, 1024, 0, stream>>>(xp_part, xp, POOL_NB);
        k_tail<<<1, 256, 0, stream>>>(xp, W2, root2, b2, lw1, lb1, lw2, lb2, out);
    } else {
        // fallback: binned rescan with as many chunks as fit (reserve pool slabs)
        size_t avail = region_floats > slab_floats ? region_floats - slab_floats : 0;
        int nchunk = (int)(avail / ((size_t)N * 6));
        if (nchunk > MAXCHUNK) nchunk = MAXCHUNK;
        if (nchunk < 1) nchunk = 1;
        float* part = regio;
        float* xp_part = part + (size_t)nchunk * N * 6;
        k_detect<<<1, 64, 0, stream>>>(ei, flag);
        k_edge_bin<<<NBINS * nchunk, 1024, 0, stream>>>(ei, x, flag, part, E, nchunk, N);
        k_node2<<<(N + 255) / 256, 256, 0, stream>>>(x, part, W1, root1, b1, h, N, nchunk);
        k_pool<<<POOL_NB, 256, 0, stream>>>(pos, h, nullptr, nullptr, W1, root1, b1,
                                            xp_part, N, POOL_NB);
        k_xpred<<<64, 1024, 0, stream>>>(xp_part, xp, POOL_NB);
        k_tail<<<1, 256, 0, stream>>>(xp, W2, root2, b2, lw1, lb1, lw2, lb2, out);
    }
}

// Round 20
// 106.286 us; speedup vs baseline: 1.2753x; 1.2753x over previous
//
#include <hip/hip_runtime.h>

#define INC 5
#define H1C 16
#define H2C 32
#define KCL 256

// fallback (rescan) params
#define NBINS 40
#define BINSZ 2500
#define MAXCHUNK 12

// partition params
#define PB_SHIFT 9
#define PB_SZ 512               // nodes per bin
#define PB_NBMAX 256
#define PB_C 18432              // bucket capacity per bin (mean 16384 + 16 sigma)
#define PB_M 6144               // edges per partition block
#define PB_ETPB 6               // PB_M / 1024
#define PB_S 2                  // phase-2 sub-splits per bin
#define PB_GMAX 9216            // max entries per gather block = PB_C/PB_S
#define PB_GETG 9               // ceil(PB_GMAX/1024)

#define POOL_NB 512
#define PCH 256                 // max nodes per pool block chunk (N<=131072/512)

typedef __attribute__((address_space(1))) const unsigned gls_src;
typedef __attribute__((address_space(3))) unsigned gls_dst;

// ---------------------------------------------------------------------------
// Fused setup: x8 expansion + gcur init + int64/int32 detect.
__global__ void k_setup(const float* __restrict__ x, float* __restrict__ x8,
                        const unsigned int* __restrict__ ei, int* __restrict__ flag,
                        unsigned* __restrict__ gcur, int N, int NB) {
    int n = blockIdx.x * blockDim.x + threadIdx.x;
    if (n < N) {
        const float* xr = x + (size_t)n * INC;
        float4* o = (float4*)(x8 + (size_t)n * 8);
        o[0] = make_float4(xr[0], xr[1], xr[2], xr[3]);
        o[1] = make_float4(xr[4], 0.0f, 0.0f, 0.0f);
    }
    if (blockIdx.x == 0) {
        if (threadIdx.x < (unsigned)NB) gcur[threadIdx.x] = (unsigned)threadIdx.x * PB_C;
        if (threadIdx.x == 0) {
            int is64 = 1;
            for (int i = 1; i < 32; i += 2)
                if (ei[i] != 0u) is64 = 0;
            *flag = is64;
        }
    }
}

// standalone detect for the fallback path
__global__ void k_detect(const unsigned int* __restrict__ ei, int* __restrict__ flag) {
    if (blockIdx.x == 0 && threadIdx.x == 0) {
        int is64 = 1;
        for (int i = 1; i < 32; i += 2)
            if (ei[i] != 0u) is64 = 0;
        *flag = is64;
    }
}

// ---------------------------------------------------------------------------
// Phase 1: partition edges into dst-bins (LDS histogram + counting sort +
// coalesced bucket writes of packed entries src<<9 | dst&511).
__global__ __launch_bounds__(1024) void k_part(const unsigned int* __restrict__ ei,
                                               const int* __restrict__ flag,
                                               unsigned* __restrict__ gcur,
                                               unsigned* __restrict__ bucket,
                                               int E, int NB) {
    __shared__ int hist[PB_NBMAX];
    __shared__ int lbase[PB_NBMAX];
    __shared__ unsigned gbase[PB_NBMAX];
    __shared__ int sc[PB_NBMAX];
    __shared__ unsigned sorted[PB_M];
    __shared__ unsigned char sbin[PB_M];

    const int tid = threadIdx.x;
    const int e0 = blockIdx.x * PB_M;
    int m = E - e0; if (m > PB_M) m = PB_M;

    for (int i = tid; i < PB_NBMAX; i += 1024) hist[i] = 0;
    __syncthreads();

    const int is64 = *flag;  // uniform
    unsigned ee[PB_ETPB]; int eb[PB_ETPB]; int er[PB_ETPB];

#pragma unroll
    for (int ii = 0; ii < PB_ETPB; ii++) {
        const int off = tid + ii * 1024;
        eb[ii] = -1; ee[ii] = 0u; er[ii] = 0;
        if (off < m) {
            const int e = e0 + off;
            unsigned d, s;
            if (is64) { d = ei[2 * ((size_t)E + (size_t)e)]; s = ei[2 * (size_t)e]; }
            else      { d = ei[(size_t)E + (size_t)e];       s = ei[(size_t)e]; }
            const int b = (int)(d >> PB_SHIFT);
            eb[ii] = b;
            ee[ii] = (s << PB_SHIFT) | (d & (PB_SZ - 1));
            er[ii] = atomicAdd(&hist[b], 1);
        }
    }
    __syncthreads();

    // inclusive scan of hist (256 entries, Hillis-Steele)
    if (tid < PB_NBMAX) sc[tid] = hist[tid];
    __syncthreads();
    for (int st = 1; st < PB_NBMAX; st <<= 1) {
        int v = 0;
        if (tid < PB_NBMAX && tid >= st) v = sc[tid - st];
        __syncthreads();
        if (tid < PB_NBMAX) sc[tid] += v;
        __syncthreads();
    }
    if (tid < PB_NBMAX) lbase[tid] = sc[tid] - hist[tid];
    if (tid < NB) gbase[tid] = atomicAdd(&gcur[tid], (unsigned)hist[tid]);
    __syncthreads();

#pragma unroll
    for (int ii = 0; ii < PB_ETPB; ii++) {
        if (eb[ii] >= 0) {
            const int j = lbase[eb[ii]] + er[ii];
            sorted[j] = ee[ii];
            sbin[j] = (unsigned char)eb[ii];
        }
    }
    __syncthreads();

    for (int j = tid; j < m; j += 1024) {
        const int b = (int)sbin[j];
        const unsigned g = gbase[b] + (unsigned)(j - lbase[b]);
        if (g < (unsigned)(b + 1) * PB_C) bucket[g] = sorted[j];  // overflow guard
    }
}

// ---------------------------------------------------------------------------
// Phase 2 (atomic-free accumulate): counting-sort the slice by local dst in
// LDS, then 2 threads per node accumulate x8[src] in REGISTERS.
__global__ __launch_bounds__(1024) void k_gather(const unsigned* __restrict__ bucket,
                                                 const unsigned* __restrict__ gcur,
                                                 const float* __restrict__ x8,
                                                 float* __restrict__ part,
                                                 int N, int NB) {
    __shared__ unsigned sorted[PB_GMAX];   // 36 KB
    __shared__ int hist[PB_SZ];
    __shared__ int sc[PB_SZ];
    __shared__ int lbase[PB_SZ];
    __shared__ float stage[PB_SZ * 6];     // 12 KB

    const int b = blockIdx.x / PB_S;
    const int sub = blockIdx.x % PB_S;
    const int tid = threadIdx.x;
    const int lo = b << PB_SHIFT;
    int hi = lo + PB_SZ; if (hi > N) hi = N;
    const int nloc = hi - lo;

    int cnt = (int)(gcur[b] - (unsigned)b * PB_C);
    if (cnt > PB_C) cnt = PB_C;
    const int i0 = (cnt * sub) / PB_S;
    const int i1 = (cnt * (sub + 1)) / PB_S;
    const int m = i1 - i0;
    const unsigned* bk = bucket + (size_t)b * PB_C + i0;

    for (int i = tid; i < PB_SZ; i += 1024) hist[i] = 0;
    __syncthreads();

    unsigned ee[PB_GETG]; int edl[PB_GETG]; int er[PB_GETG];
#pragma unroll
    for (int ii = 0; ii < PB_GETG; ii++) {
        const int off = tid + ii * 1024;
        edl[ii] = -1; ee[ii] = 0u; er[ii] = 0;
        if (off < m) {
            const unsigned e = bk[off];
            const int dl = (int)(e & (PB_SZ - 1));
            edl[ii] = dl;
            ee[ii] = e;
            er[ii] = atomicAdd(&hist[dl], 1);
        }
    }
    __syncthreads();

    // exclusive scan of 512-entry hist
    if (tid < PB_SZ) sc[tid] = hist[tid];
    __syncthreads();
    for (int st = 1; st < PB_SZ; st <<= 1) {
        int v = 0;
        if (tid < PB_SZ && tid >= st) v = sc[tid - st];
        __syncthreads();
        if (tid < PB_SZ) sc[tid] += v;
        __syncthreads();
    }
    if (tid < PB_SZ) lbase[tid] = sc[tid] - hist[tid];
    __syncthreads();

#pragma unroll
    for (int ii = 0; ii < PB_GETG; ii++)
        if (edl[ii] >= 0) sorted[lbase[edl[ii]] + er[ii]] = ee[ii];
    __syncthreads();

    // register accumulation: 2 threads per node, half a run each
    const int node = tid & (PB_SZ - 1);
    const int half = tid >> PB_SHIFT;      // 0 or 1
    const int start = lbase[node];
    const int len = hist[node];
    const int js = start + (half ? (len >> 1) : 0);
    const int je = start + (half ? len : (len >> 1));
    float a0 = 0.f, a1 = 0.f, a2 = 0.f, a3 = 0.f, a4 = 0.f;
    for (int j = js; j < je; j++) {
        const unsigned s = sorted[j] >> PB_SHIFT;
        const float4 xr4 = *(const float4*)(x8 + (size_t)s * 8);
        const float xr5 = x8[(size_t)s * 8 + 4];
        a0 += xr4.x; a1 += xr4.y; a2 += xr4.z; a3 += xr4.w; a4 += xr5;
    }
    if (half) {
        float* st = stage + node * 6;
        st[0] = a0; st[1] = a1; st[2] = a2; st[3] = a3; st[4] = a4;
    }
    __syncthreads();
    if (!half && node < nloc) {
        const float* st = stage + node * 6;
        float* o = part + (size_t)sub * ((size_t)N * 6) + (size_t)(lo + node) * 6;
        o[0] = a0 + st[0];
        o[1] = a1 + st[1];
        o[2] = a2 + st[2];
        o[3] = a3 + st[3];
        o[4] = a4 + st[4];
        o[5] = (float)len;
    }
}

// ---------------------------------------------------------------------------
// Fallback binned-rescan edge kernel.
__global__ __launch_bounds__(1024) void k_edge_bin(const unsigned int* __restrict__ ei,
                                                   const float* __restrict__ x,
                                                   const int* __restrict__ flag,
                                                   float* __restrict__ part,
                                                   int E, int nchunk, int N) {
    __shared__ float acc[BINSZ * 6];
    const int bin = blockIdx.x % NBINS;
    const int chunk = blockIdx.x / NBINS;
    const int lo = bin * BINSZ;
    const int hi = (lo + BINSZ < N) ? (lo + BINSZ) : N;
    const int nloc = hi - lo;
    for (int i = threadIdx.x; i < nloc * 6; i += 1024) acc[i] = 0.0f;
    __syncthreads();

    const int is64 = *flag;
    const long long ce = ((long long)E + nchunk - 1) / nchunk;
    const long long e0 = (long long)chunk * ce;
    long long e1 = e0 + ce;
    if (e1 > E) e1 = E;

    for (long long e = e0 + threadIdx.x; e < e1; e += 1024) {
        const int d = is64 ? (int)ei[2 * ((size_t)E + (size_t)e)] : (int)ei[(size_t)E + (size_t)e];
        if (d >= lo && d < hi) {
            const int s = is64 ? (int)ei[2 * (size_t)e] : (int)ei[(size_t)e];
            const float* xr = x + (size_t)s * INC;
            float* a = acc + (d - lo) * 6;
            atomicAdd(a + 0, xr[0]);
            atomicAdd(a + 1, xr[1]);
            atomicAdd(a + 2, xr[2]);
            atomicAdd(a + 3, xr[3]);
            atomicAdd(a + 4, xr[4]);
            atomicAdd(a + 5, 1.0f);
        }
    }
    __syncthreads();
    float* o = part + (size_t)chunk * ((size_t)N * 6) + (size_t)lo * 6;
    for (int i = threadIdx.x; i < nloc * 6; i += 1024) o[i] = acc[i];
}

// ---------------------------------------------------------------------------
// Reduce partials + node update (FALLBACK PATH ONLY; fast path fuses into pool).
__global__ void k_node2(const float* __restrict__ x, const float* __restrict__ part,
                        const float* __restrict__ W1, const float* __restrict__ root1,
                        const float* __restrict__ b1, float* __restrict__ h,
                        int N, int nchunk) {
    int n = blockIdx.x * blockDim.x + threadIdx.x;
    if (n >= N) return;
    float s[6] = {0.f, 0.f, 0.f, 0.f, 0.f, 0.f};
    for (int c = 0; c < nchunk; c++) {
        const float* p = part + (size_t)c * ((size_t)N * 6) + (size_t)n * 6;
#pragma unroll
        for (int j = 0; j < 6; j++) s[j] += p[j];
    }
    const float inv = 1.0f / fmaxf(s[5], 1.0f);
    float xs[INC], xv[INC];
#pragma unroll
    for (int c = 0; c < INC; c++) {
        xs[c] = s[c] * inv;
        xv[c] = x[(size_t)n * INC + c];
    }
    float hv[H1C];
#pragma unroll
    for (int j = 0; j < H1C; j++) {
        float v = b1[j];
#pragma unroll
        for (int c = 0; c < INC; c++)
            v = fmaf(xs[c], W1[c * H1C + j], fmaf(xv[c], root1[c * H1C + j], v));
        hv[j] = fmaxf(v, 0.0f);  // relu(leaky(relu(v))) == relu(v)
    }
    float4* hp = (float4*)(h + (size_t)n * H1C);
#pragma unroll
    for (int q = 0; q < 4; q++)
        hp[q] = make_float4(hv[4 * q], hv[4 * q + 1], hv[4 * q + 2], hv[4 * q + 3]);
}

// ---------------------------------------------------------------------------
// Pooling GEMM, depth-4 register pipeline (modulo schedule, no rotation):
// thread = (lane -> col-quad); wave -> node stride 4. Four NAMED float4
// groups A/B/C/D; body: compute G_k on its buffer, then reload that buffer
// with G_{k+4}. Reload-to-use distance = 3 compute groups >> HBM latency.
// h rows: fused-compute from part+x8 (fast path) or staged from h (fallback).
__global__ __launch_bounds__(256) void k_pool(const float* __restrict__ pos,
                                              const float* __restrict__ h,
                                              const float* __restrict__ part,
                                              const float* __restrict__ x8,
                                              const float* __restrict__ W1,
                                              const float* __restrict__ root1,
                                              const float* __restrict__ b1,
                                              float* __restrict__ xp_part, int N, int nb) {
    __shared__ float hbuf[PCH * H1C];      // 16 KB
    __shared__ float sred[2][32][64];      // 16 KB reduce scratch
    const int tid = threadIdx.x;
    const int lane = tid & 63;
    const int w = tid >> 6;
    const int chunk = (N + nb - 1) / nb;   // <= PCH
    const int n0 = blockIdx.x * chunk;
    const int n1 = min(n0 + chunk, N);
    const int cnt = (n1 > n0) ? (n1 - n0) : 0;

    if (part) {
        // fused h-compute: thread t -> node n0+t
        if (tid < cnt) {
            const int n = n0 + tid;
            const float* pa = part + (size_t)n * 6;
            const float* pb = part + (size_t)N * 6 + (size_t)n * 6;
            float s[6];
#pragma unroll
            for (int j = 0; j < 6; j++) s[j] = pa[j] + pb[j];
            const float inv = 1.0f / fmaxf(s[5], 1.0f);
            float xs[INC], xv[INC];
#pragma unroll
            for (int c = 0; c < INC; c++) {
                xs[c] = s[c] * inv;
                xv[c] = x8[(size_t)n * 8 + c];
            }
#pragma unroll
            for (int j = 0; j < H1C; j++) {
                float v = b1[j];
#pragma unroll
                for (int c = 0; c < INC; c++)
                    v = fmaf(xs[c], W1[c * H1C + j], fmaf(xv[c], root1[c * H1C + j], v));
                hbuf[tid * H1C + j] = fmaxf(v, 0.0f);
            }
        }
    } else {
        // fallback: stage h rows from global
        const size_t maxh = (size_t)N * H1C - 4;
        for (int ii = w; ii * 256 < cnt * H1C; ii += 4) {
            size_t fi = (size_t)n0 * H1C + (size_t)ii * 256 + (size_t)lane * 4;
            if (fi > maxh) fi = maxh;
            __builtin_amdgcn_global_load_lds((gls_src*)(h + fi),
                                             (gls_dst*)&hbuf[ii * 256], 16, 0, 0);
        }
    }
    __syncthreads();

    float acc[4][H1C];
#pragma unroll
    for (int c = 0; c < 4; c++)
#pragma unroll
        for (int d = 0; d < H1C; d++) acc[c][d] = 0.0f;

    const float4* pos4 = (const float4*)pos;
    const float4 z4 = make_float4(0.f, 0.f, 0.f, 0.f);

#define LDP(dst, i)                                                        \
    {                                                                      \
        const int _i = (i);                                                \
        if (_i < cnt) dst = pos4[((size_t)n0 + _i) * 64 + lane];           \
    }
#define CMP(i, p)                                                          \
    {                                                                      \
        const int _i = (i);                                                \
        if (_i < cnt) {                                                    \
            const float4 h0 = *(const float4*)&hbuf[_i * H1C + 0];         \
            const float4 h1 = *(const float4*)&hbuf[_i * H1C + 4];         \
            const float4 h2 = *(const float4*)&hbuf[_i * H1C + 8];         \
            const float4 h3 = *(const float4*)&hbuf[_i * H1C + 12];        \
            const float pk[4] = {p.x, p.y, p.z, p.w};                      \
            const float hv[H1C] = {h0.x, h0.y, h0.z, h0.w,                 \
                                   h1.x, h1.y, h1.z, h1.w,                 \
                                   h2.x, h2.y, h2.z, h2.w,                 \
                                   h3.x, h3.y, h3.z, h3.w};                \
            _Pragma("unroll")                                              \
            for (int c = 0; c < 4; c++)                                    \
                _Pragma("unroll")                                          \
                for (int d = 0; d < H1C; d++)                              \
                    acc[c][d] = fmaf(pk[c], hv[d], acc[c][d]);             \
        }                                                                  \
    }

    float4 A0 = z4, A1 = z4, A2 = z4, A3 = z4;
    float4 B0 = z4, B1 = z4, B2 = z4, B3 = z4;
    float4 C0 = z4, C1 = z4, C2 = z4, C3 = z4;
    float4 D0 = z4, D1 = z4, D2 = z4, D3 = z4;
    LDP(A0, w + 0)  LDP(A1, w + 4)  LDP(A2, w + 8)  LDP(A3, w + 12)
    LDP(B0, w + 16) LDP(B1, w + 20) LDP(B2, w + 24) LDP(B3, w + 28)
    LDP(C0, w + 32) LDP(C1, w + 36) LDP(C2, w + 40) LDP(C3, w + 44)
    LDP(D0, w + 48) LDP(D1, w + 52) LDP(D2, w + 56) LDP(D3, w + 60)
    for (int i = w; i < cnt; i += 64) {
        CMP(i + 0, A0)  CMP(i + 4, A1)  CMP(i + 8, A2)  CMP(i + 12, A3)
        LDP(A0, i + 64) LDP(A1, i + 68) LDP(A2, i + 72) LDP(A3, i + 76)
        CMP(i + 16, B0) CMP(i + 20, B1) CMP(i + 24, B2) CMP(i + 28, B3)
        LDP(B0, i + 80) LDP(B1, i + 84) LDP(B2, i + 88) LDP(B3, i + 92)
        CMP(i + 32, C0) CMP(i + 36, C1) CMP(i + 40, C2) CMP(i + 44, C3)
        LDP(C0, i + 96) LDP(C1, i + 100) LDP(C2, i + 104) LDP(C3, i + 108)
        CMP(i + 48, D0) CMP(i + 52, D1) CMP(i + 56, D2) CMP(i + 60, D3)
        LDP(D0, i + 112) LDP(D1, i + 116) LDP(D2, i + 120) LDP(D3, i + 124)
    }
#undef LDP
#undef CMP

    // ---- cross-wave reduce: two 32-value chunks, [val][lane] conflict-free
    __syncthreads();
#pragma unroll
    for (int ch = 0; ch < 2; ch++) {
        if (w == 1 || w == 3) {
            float* sl = &sred[(w - 1) >> 1][0][0] + lane;
#pragma unroll
            for (int v = 0; v < 32; v++) sl[v * 64] = acc[ch * 2 + (v >> 4)][v & 15];
        }
        __syncthreads();
        if (w == 0 || w == 2) {
            const float* sl = &sred[w >> 1][0][0] + lane;
#pragma unroll
            for (int v = 0; v < 32; v++) acc[ch * 2 + (v >> 4)][v & 15] += sl[v * 64];
        }
        __syncthreads();
        if (w == 2) {
            float* sl = &sred[0][0][0] + lane;
#pragma unroll
            for (int v = 0; v < 32; v++) sl[v * 64] = acc[ch * 2 + (v >> 4)][v & 15];
        }
        __syncthreads();
        if (w == 0) {
            const float* sl = &sred[0][0][0] + lane;
#pragma unroll
            for (int v = 0; v < 32; v++) acc[ch * 2 + (v >> 4)][v & 15] += sl[v * 64];
        }
        __syncthreads();
    }
    if (w == 0) {
        float* o = xp_part + (size_t)blockIdx.x * (KCL * H1C);
#pragma unroll
        for (int c = 0; c < 4; c++) {
            float* oc = o + (4 * lane + c) * H1C;
            *(float4*)(oc + 0)  = make_float4(acc[c][0],  acc[c][1],  acc[c][2],  acc[c][3]);
            *(float4*)(oc + 4)  = make_float4(acc[c][4],  acc[c][5],  acc[c][6],  acc[c][7]);
            *(float4*)(oc + 8)  = make_float4(acc[c][8],  acc[c][9],  acc[c][10], acc[c][11]);
            *(float4*)(oc + 12) = make_float4(acc[c][12], acc[c][13], acc[c][14], acc[c][15]);
        }
    }
}

// ---------------------------------------------------------------------------
__global__ __launch_bounds__(1024) void k_xpred(const float* __restrict__ xp_part,
                                                float* __restrict__ xp, int nb) {
    __shared__ float r[1024];
    const int li = threadIdx.x & 63;
    const int sub = threadIdx.x >> 6;      // 0..15
    const int i = blockIdx.x * 64 + li;
    float s = 0.0f;
    for (int b = sub; b < nb; b += 16) s += xp_part[(size_t)b * (KCL * H1C) + i];
    r[threadIdx.x] = s;
    __syncthreads();
    if (threadIdx.x < 512) r[threadIdx.x] += r[threadIdx.x + 512];
    __syncthreads();
    if (threadIdx.x < 256) r[threadIdx.x] += r[threadIdx.x + 256];
    __syncthreads();
    if (threadIdx.x < 128) r[threadIdx.x] += r[threadIdx.x + 128];
    __syncthreads();
    if (threadIdx.x < 64) xp[i] = r[threadIdx.x] + r[threadIdx.x + 64];
}

// ---------------------------------------------------------------------------
// Tail: adj strictly positive => mask all-ones, deg2 = 256.
// Column sums via register butterfly (__shfl_xor).
__global__ __launch_bounds__(256) void k_tail(const float* __restrict__ xp,
                                              const float* __restrict__ W2,
                                              const float* __restrict__ root2,
                                              const float* __restrict__ b2,
                                              const float* __restrict__ lw1,
                                              const float* __restrict__ lb1,
                                              const float* __restrict__ lw2,
                                              const float* __restrict__ lb2,
                                              float* __restrict__ out) {
    __shared__ float red[4][H2C];
    __shared__ float bcast[H2C];
    const int t = threadIdx.x;
    const int wv = t >> 6;
    const int lane = t & 63;

    float row[H1C];
#pragma unroll
    for (int c = 0; c < H1C; c++) row[c] = xp[t * H1C + c];

    float v1[H2C];
#pragma unroll
    for (int j = 0; j < H2C; j++) {
        float v = 0.0f;
#pragma unroll
        for (int c = 0; c < H1C; c++) v = fmaf(row[c], W2[c * H2C + j], v);
        v1[j] = v;
    }
#pragma unroll
    for (int off = 1; off < 64; off <<= 1) {
#pragma unroll
        for (int j = 0; j < H2C; j++) v1[j] += __shfl_xor(v1[j], off);
    }
    if (lane == 0) {
#pragma unroll
        for (int j = 0; j < H2C; j++) red[wv][j] = v1[j];
    }
    __syncthreads();
    if (t < H2C) bcast[t] = red[0][t] + red[1][t] + red[2][t] + red[3][t];
    __syncthreads();

    float v2[H2C];
#pragma unroll
    for (int j = 0; j < H2C; j++) {
        float v = bcast[j] * (1.0f / KCL) + b2[j];
#pragma unroll
        for (int c = 0; c < H1C; c++) v = fmaf(row[c], root2[c * H2C + j], v);
        v2[j] = fmaxf(v, 0.0f);
    }
#pragma unroll
    for (int off = 1; off < 64; off <<= 1) {
#pragma unroll
        for (int j = 0; j < H2C; j++) v2[j] += __shfl_xor(v2[j], off);
    }
    if (lane == 0) {
#pragma unroll
        for (int j = 0; j < H2C; j++) red[wv][j] = v2[j];
    }
    __syncthreads();

    if (t == 0) {
        float g[H2C];
#pragma unroll
        for (int j = 0; j < H2C; j++)
            g[j] = (red[0][j] + red[1][j] + red[2][j] + red[3][j]) * (1.0f / KCL);
        float u[8];
#pragma unroll
        for (int a = 0; a < 8; a++) {
            float v = lb1[a];
#pragma unroll
            for (int j = 0; j < H2C; j++) v = fmaf(g[j], lw1[j * 8 + a], v);
            u[a] = v > 0.0f ? v : 0.1f * v;
        }
#pragma unroll
        for (int o = 0; o < 2; o++) {
            float v = lb2[o];
#pragma unroll
            for (int a = 0; a < 8; a++) v = fmaf(u[a], lw2[a * 2 + o], v);
            out[o] = v;
        }
    }
}

// ---------------------------------------------------------------------------
extern "C" void kernel_launch(void* const* d_in, const int* in_sizes, int n_in,
                              void* d_out, int out_size, void* d_ws, size_t ws_size,
                              hipStream_t stream) {
    const float* x         = (const float*)d_in[0];
    const unsigned int* ei = (const unsigned int*)d_in[1];
    // d_in[2] = edge_attr: unused (adj has no exact zeros -> mask all-ones)
    const float* pos   = (const float*)d_in[3];
    const float* W1    = (const float*)d_in[4];
    const float* root1 = (const float*)d_in[5];
    const float* b1    = (const float*)d_in[6];
    const float* W2    = (const float*)d_in[7];
    const float* root2 = (const float*)d_in[8];
    const float* b2    = (const float*)d_in[9];
    const float* lw1   = (const float*)d_in[10];
    const float* lb1   = (const float*)d_in[11];
    const float* lw2   = (const float*)d_in[12];
    const float* lb2   = (const float*)d_in[13];
    float* out = (float*)d_out;

    const int N = in_sizes[0] / INC;  // 100000
    const int E = in_sizes[1] / 2;    // 3200000
    const int NB = (N + PB_SZ - 1) >> PB_SHIFT;

    // workspace prefix (floats): [xp 4096][flag 16][h N*16][REGION ...]
    float* ws    = (float*)d_ws;
    float* xp    = ws;
    int*   flag  = (int*)(xp + KCL * H1C);
    float* h     = (float*)(flag + 16);
    float* regio = h + (size_t)N * H1C;

    const size_t pref_floats = (size_t)(KCL * H1C) + 16 + (size_t)N * H1C;
    const size_t region_floats = ws_size / 4 > pref_floats ? ws_size / 4 - pref_floats : 0;
    // fast path region: part[PB_S*N*6] | x8[N*8] | max(bucket[NB*PB_C]+gcur, xp_part slabs)
    const size_t slab_floats = (size_t)POOL_NB * (KCL * H1C);
    const size_t buck_floats = (size_t)NB * PB_C + 256;
    const size_t fast_floats = (size_t)PB_S * N * 6 + (size_t)N * 8 +
                               (buck_floats > slab_floats ? buck_floats : slab_floats);

    if (region_floats >= fast_floats && N <= 131072 && NB <= PB_NBMAX) {
        float* part      = regio;
        float* x8        = part + (size_t)PB_S * N * 6;
        unsigned* bucket = (unsigned*)(x8 + (size_t)N * 8);
        unsigned* gcur   = bucket + (size_t)NB * PB_C;
        const int P = (E + PB_M - 1) / PB_M;

        k_setup<<<(N + 255) / 256, 256, 0, stream>>>(x, x8, ei, flag, gcur, N, NB);
        k_part<<<P, 1024, 0, stream>>>(ei, flag, gcur, bucket, E, NB);
        k_gather<<<NB * PB_S, 1024, 0, stream>>>(bucket, gcur, x8, part, N, NB);

        // pool fuses node-update (reads part + x8); xp_part overwrites bucket
        // (dead after k_gather); x8 stays live.
        float* xp_part = (float*)bucket;
        k_pool<<<POOL_NB, 256, 0, stream>>>(pos, nullptr, part, x8, W1, root1, b1,
                                            xp_part, N, POOL_NB);
        k_xpred<<<64, 1024, 0, stream>>>(xp_part, xp, POOL_NB);
        k_tail<<<1, 256, 0, stream>>>(xp, W2, root2, b2, lw1, lb1, lw2, lb2, out);
    } else {
        // fallback: binned rescan with as many chunks as fit (reserve pool slabs)
        size_t avail = region_floats > slab_floats ? region_floats - slab_floats : 0;
        int nchunk = (int)(avail / ((size_t)N * 6));
        if (nchunk > MAXCHUNK) nchunk = MAXCHUNK;
        if (nchunk < 1) nchunk = 1;
        float* part = regio;
        float* xp_part = part + (size_t)nchunk * N * 6;
        k_detect<<<1, 64, 0, stream>>>(ei, flag);
        k_edge_bin<<<NBINS * nchunk, 1024, 0, stream>>>(ei, x, flag, part, E, nchunk, N);
        k_node2<<<(N + 255) / 256, 256, 0, stream>>>(x, part, W1, root1, b1, h, N, nchunk);
        k_pool<<<POOL_NB, 256, 0, stream>>>(pos, h, nullptr, nullptr, W1, root1, b1,
                                            xp_part, N, POOL_NB);
        k_xpred<<<64, 1024, 0, stream>>>(xp_part, xp, POOL_NB);
        k_tail<<<1, 256, 0, stream>>>(xp, W2, root2, b2, lw1, lb1, lw2, lb2, out);
    }
}